// Round 10
// baseline (385.484 us; speedup 1.0000x reference)
//
#include <hip/hip_runtime.h>
#include <hip/hip_cooperative_groups.h>
#include <stdint.h>

#define DDIM 2048
#define LDIM 2048
#define BDIM 2
#define CATK 18432    // 9*D  (original W col count)
#define MDIM 4096     // B*L
#define NDIM 2048
#define KGEMM 12288   // 6*D : [silu(x) | inner1 | inner2 | inner4 | inner8 | x]
#define KCHUNK 6144   // split-K=2; also the row stride of B0/B1

typedef short bf16x8 __attribute__((ext_vector_type(8)));
typedef float f32x4 __attribute__((ext_vector_type(4)));
typedef unsigned short u16x8 __attribute__((ext_vector_type(8)));

__device__ __forceinline__ unsigned short f2bf(float f) {
  uint32_t u = __float_as_uint(f);
  return (unsigned short)((u + 0x7fffu + ((u >> 16) & 1u)) >> 16);
}
__device__ __forceinline__ float bf2f(unsigned short h) {
  return __uint_as_float((uint32_t)h << 16);
}
__device__ __forceinline__ float silu_f(float v) { return v / (1.0f + __expf(-v)); }

__device__ __forceinline__ void async16(const void* g, void* l) {
  __builtin_amdgcn_global_load_lds(
      (const __attribute__((address_space(1))) uint32_t*)(uintptr_t)g,
      (__attribute__((address_space(3))) uint32_t*)(uintptr_t)l, 16, 0, 0);
}

// ---------- glo = mean_L(x) : two-stage ----------
__global__ __launch_bounds__(256) void glo_partial(const float* __restrict__ x,
                                                   float* __restrict__ part) {
  int g = blockIdx.x;                 // 256 blocks = b(2) * sl(16) * dc(8)
  int dc = g & 7, sl = (g >> 3) & 15, b = g >> 7;
  int d = dc * 256 + threadIdx.x;
  const float* p = x + ((size_t)b * LDIM + (size_t)sl * 128) * DDIM + d;
  float s = 0.f;
  #pragma unroll 8
  for (int i = 0; i < 128; ++i) s += p[(size_t)i * DDIM];
  part[(size_t)(b * 16 + sl) * DDIM + d] = s;
}

__global__ __launch_bounds__(256) void glo_final(const float* __restrict__ part,
                                                 float* __restrict__ glo) {
  int idx = blockIdx.x * 256 + threadIdx.x;   // 0..4095 = b*2048+d
  int b = idx >> 11, d = idx & 2047;
  float s = 0.f;
  #pragma unroll
  for (int i = 0; i < 16; ++i) s += part[(size_t)(b * 16 + i) * DDIM + d];
  glo[idx] = s * (1.0f / (float)LDIM);
}

// ---------- W common blocks f32 -> bf16 into per-chunk B arrays ----------
// B0[o][6144]     <- W blocks {0(silu),1(i1),3(i2)}   written ONCE
// B1[b][o][6144]  <- cols 0..4095: W blocks {5(i4),7(i8)} duplicated per b
//                    cols 4096..6143: V_b (written by fold_w)
__global__ __launch_bounds__(256) void conv_wB(const float* __restrict__ W,
                                               unsigned short* __restrict__ B0,
                                               unsigned short* __restrict__ B1) {
  int k = blockIdx.x;                 // 0..4
  int o = blockIdx.y;                 // row 0..2047
  int srcb = (k == 0) ? 0 : (k == 1) ? 1 : (k == 2) ? 3 : (k == 3) ? 5 : 7;
  const float* src = W + (size_t)o * CATK + srcb * 2048 + threadIdx.x * 8;
  f32x4 a = *(const f32x4*)src;
  f32x4 c = *(const f32x4*)(src + 4);
  u16x8 v;
  v[0] = f2bf(a[0]); v[1] = f2bf(a[1]); v[2] = f2bf(a[2]); v[3] = f2bf(a[3]);
  v[4] = f2bf(c[0]); v[5] = f2bf(c[1]); v[6] = f2bf(c[2]); v[7] = f2bf(c[3]);
  if (k < 3) {
    *(u16x8*)(B0 + (size_t)o * KCHUNK + k * 2048 + threadIdx.x * 8) = v;
  } else {
    size_t d = (size_t)o * KCHUNK + (size_t)(k - 3) * 2048 + threadIdx.x * 8;
    *(u16x8*)(B1 + d) = v;
    *(u16x8*)(B1 + (size_t)2048 * KCHUNK + d) = v;
  }
}

// ---------- fold wedge blocks into per-batch effective weights ----------
// V_b[o,d] = sum_s ( Ws[o,d]*g_b[(d-s)&2047] - Ws[o,(d+s)&2047]*g_b[(d+s)&2047] )
// s = 1,2,4,8 ; Ws = W block (2+2j). Both batches per block: W read ONCE.
// Written to B1[b][o][4096 + d].
__global__ __launch_bounds__(256) void fold_w(const float* __restrict__ W,
                                              const float* __restrict__ glo,
                                              unsigned short* __restrict__ B1) {
  __shared__ float ws[4][2048];
  __shared__ float g2[2][2048];
  int o = blockIdx.x;
  for (int i = threadIdx.x; i < 512; i += 256) {
    *(f32x4*)&g2[0][i * 4] = *(const f32x4*)&glo[i * 4];
    *(f32x4*)&g2[1][i * 4] = *(const f32x4*)&glo[2048 + i * 4];
    #pragma unroll
    for (int j = 0; j < 4; ++j)
      *(f32x4*)&ws[j][i * 4] =
          *(const f32x4*)(W + (size_t)o * CATK + (2 + 2 * j) * 2048 + i * 4);
  }
  __syncthreads();
  int d0 = threadIdx.x * 8;
  #pragma unroll
  for (int b = 0; b < 2; ++b) {
    u16x8 outv;
    #pragma unroll
    for (int e = 0; e < 8; ++e) {
      int d = d0 + e;
      float v = 0.f;
      #pragma unroll
      for (int j = 0; j < 4; ++j) {
        int s = 1 << j;
        int dm = (d - s) & 2047, dp = (d + s) & 2047;
        v += ws[j][d] * g2[b][dm] - ws[j][dp] * g2[b][dp];
      }
      outv[e] = f2bf(v);
    }
    *(u16x8*)(B1 + (size_t)b * 2048 * KCHUNK + (size_t)o * KCHUNK + 4096 + d0) = outv;
  }
}

// ---------- build A features (bf16): [silu(x) | inner(1,2,4,8) | x] ----------
__global__ __launch_bounds__(256) void build_mixed(const float* __restrict__ x,
                                                   const float* __restrict__ glo,
                                                   unsigned short* __restrict__ mixed) {
  __shared__ float xs[DDIM];
  __shared__ float gs[DDIM];
  int row = blockIdx.x;              // 0..4095
  int b = row >> 11;
  const float* xr = x + (size_t)row * DDIM;
  const float* gr = glo + (size_t)b * DDIM;
  for (int i = threadIdx.x; i < DDIM / 4; i += 256) {
    *(f32x4*)&xs[i * 4] = *(const f32x4*)&xr[i * 4];
    *(f32x4*)&gs[i * 4] = *(const f32x4*)&gr[i * 4];
  }
  __syncthreads();
  unsigned short* mr = mixed + (size_t)row * KGEMM;
  int d0 = threadIdx.x * 8;
  u16x8 o0, oi[4], xb;
  #pragma unroll
  for (int j = 0; j < 8; ++j) {
    int d = d0 + j;
    float xv = xs[d];
    o0[j] = f2bf(silu_f(xv));
    xb[j] = f2bf(xv);
    #pragma unroll
    for (int si = 0; si < 4; ++si) {
      int s = 1 << si;
      int dm = (d - s) & (DDIM - 1);
      oi[si][j] = f2bf(silu_f(xv * gs[dm]));
    }
  }
  *(u16x8*)(mr + d0) = o0;
  #pragma unroll
  for (int si = 0; si < 4; ++si)
    *(u16x8*)(mr + (size_t)(1 + si) * DDIM + d0) = oi[si];
  *(u16x8*)(mr + (size_t)10240 + d0) = xb;
}

// ---------- 256x256 8-phase GEMM (T2+T3+T4+T5), split-K=2 ----------
// ROUND-10: same proven schedule as round-9 (180us, MfmaUtil 51%). NEW:
// cooperative fused epilogue — kc=1 writes P1 bf16, grid.sync() (co-resident
// by construction: 256 blocks, 1/CU), kc=0 keeps acc in registers across the
// sync and writes out = acc + bias + f32(P1) directly. Kills the combine
// kernel + P0 round-trip. coop=0 falls back to the round-9 two-kernel path
// (no thread calls grid.sync then — uniform).
#define BAR() __builtin_amdgcn_s_barrier()
#define SCHEDB() __builtin_amdgcn_sched_barrier(0)
#define WAIT_VM4() asm volatile("s_waitcnt vmcnt(4)" ::: "memory")
#define WAIT_VM0() asm volatile("s_waitcnt vmcnt(0)" ::: "memory")
#define WAIT_LGKM0() asm volatile("s_waitcnt lgkmcnt(0)" ::: "memory")

#define STAGE_A(S, H, KREL)                                            \
  do {                                                                 \
    const unsigned short* g_ = gA + (size_t)((H)*128) * KGEMM + (KREL);\
    unsigned short* l_ = stA + ((S)*2 + (H)) * 8192;                   \
    async16(g_, l_);                                                   \
    async16(g_ + (size_t)8 * KGEMM, l_ + 512);                         \
  } while (0)

#define STAGE_B(S, H, KREL)                                             \
  do {                                                                  \
    const unsigned short* g_ = gB + (size_t)((H)*128) * KCHUNK + (KREL);\
    unsigned short* l_ = stB + ((S)*2 + (H)) * 8192;                    \
    async16(g_, l_);                                                    \
    async16(g_ + (size_t)8 * KCHUNK, l_ + 512);                         \
  } while (0)

#define LOAD_A(S, MH)                                                        \
  do {                                                                       \
    _Pragma("unroll") for (int mi = 0; mi < 4; ++mi) {                       \
      ra[mi][0] = *(const bf16x8*)(pA + (S)*16384 + ((MH)*64 + mi*16)*64 + sl0); \
      ra[mi][1] = *(const bf16x8*)(pA + (S)*16384 + ((MH)*64 + mi*16)*64 + sl1); \
    }                                                                        \
  } while (0)

#define LOAD_B(S, NH, RB)                                                    \
  do {                                                                       \
    _Pragma("unroll") for (int nj = 0; nj < 2; ++nj) {                       \
      RB[nj][0] = *(const bf16x8*)(pB + (S)*16384 + ((NH)*32 + nj*16)*64 + sl0); \
      RB[nj][1] = *(const bf16x8*)(pB + (S)*16384 + ((NH)*32 + nj*16)*64 + sl1); \
    }                                                                        \
  } while (0)

#define MFMA_QUAD(MH, NH, RB)                                                \
  do {                                                                       \
    __builtin_amdgcn_s_setprio(1);                                           \
    _Pragma("unroll") for (int kk = 0; kk < 2; ++kk)                         \
      _Pragma("unroll") for (int mi = 0; mi < 4; ++mi)                       \
        _Pragma("unroll") for (int nj = 0; nj < 2; ++nj)                     \
          acc[(MH)*4 + mi][(NH)*2 + nj] = __builtin_amdgcn_mfma_f32_16x16x32_bf16( \
              ra[mi][kk], RB[nj][kk], acc[(MH)*4 + mi][(NH)*2 + nj], 0, 0, 0);     \
    __builtin_amdgcn_s_setprio(0);                                           \
  } while (0)

__global__ __launch_bounds__(512, 2) void gemm256(const unsigned short* __restrict__ A,
                                                  const unsigned short* __restrict__ B0,
                                                  const unsigned short* __restrict__ B1,
                                                  const float* __restrict__ bias,
                                                  unsigned short* __restrict__ P0,
                                                  unsigned short* __restrict__ P1,
                                                  float* __restrict__ out,
                                                  int coop) {
  extern __shared__ unsigned short lds[];
  unsigned short* ldsA = lds;            // [s][h][128][64]
  unsigned short* ldsB = lds + 32768;

  int bid = blockIdx.x;                  // 256 blocks
  int swz = (bid & 7) * 32 + (bid >> 3); // XCD-contiguous, bijective (256%8==0)
  int kc = swz >> 7;                     // split-K chunk
  int rem = swz & 127;
  int mt = rem >> 3, nt = rem & 7;       // 16 x 8 tiles of 256^2
  size_t kbase = (size_t)kc * KCHUNK;

  int tid = threadIdx.x;
  int wave = tid >> 6, lane = tid & 63;
  int wr = wave >> 2, wcol = wave & 3;   // 2M x 4N waves
  int lrow = lane & 15, kq = lane >> 4, r3 = lrow & 7;
  int rIn8 = lane >> 3;
  int scOff = ((lane & 7) ^ rIn8) * 8;   // pre-swizzled source chunk
  int wv16 = wave * 16;

  const unsigned short* gA = A + (size_t)(mt * 256 + wv16 + rIn8) * KGEMM + kbase + scOff;
  const unsigned short* gBb = kc ? (B1 + (size_t)((mt >= 8) ? 2048 : 0) * KCHUNK) : B0;
  const unsigned short* gB = gBb + (size_t)(nt * 256 + wv16 + rIn8) * KCHUNK + scOff;
  unsigned short* stA = ldsA + wv16 * 64;  // wave-uniform LDS stage base
  unsigned short* stB = ldsB + wv16 * 64;

  const unsigned short* pA = ldsA + wr * 8192 + lrow * 64;
  const unsigned short* pB = ldsB + (wcol >> 1) * 8192 + ((wcol & 1) * 64 + lrow) * 64;
  int sl0 = (kq ^ r3) * 8, sl1 = ((kq + 4) ^ r3) * 8;

  f32x4 acc[8][4];
  #pragma unroll
  for (int i = 0; i < 8; ++i)
    #pragma unroll
    for (int j = 0; j < 4; ++j) acc[i][j] = (f32x4)0.f;
  bf16x8 ra[4][2], rb0[2][2], rb1[2][2];

  // ---- prologue: KT0 (s0) all 4 halves + KT1 (s1) B halves ----
  STAGE_B(0, 0, 0); STAGE_B(0, 1, 0);
  STAGE_A(0, 0, 0); STAGE_A(0, 1, 0);
  STAGE_B(1, 0, 64); STAGE_B(1, 1, 64);
  WAIT_VM4(); SCHEDB();
  BAR(); SCHEDB();

  // ---- main loop: 47 full iterations (KT 0..93), staging 2 K-tiles ahead ----
  for (int t = 0; t < 47; ++t) {
    size_t k0 = (size_t)t * 128;
    // ph1
    LOAD_A(0, 0); LOAD_B(0, 0, rb0);
    STAGE_A(1, 0, k0 + 64);
    BAR(); WAIT_LGKM0(); SCHEDB();
    MFMA_QUAD(0, 0, rb0);
    SCHEDB(); BAR(); SCHEDB();
    // ph2
    LOAD_B(0, 1, rb1);
    STAGE_A(1, 1, k0 + 64);
    BAR(); WAIT_LGKM0(); SCHEDB();
    MFMA_QUAD(0, 1, rb1);
    SCHEDB(); BAR(); SCHEDB();
    // ph3
    LOAD_A(0, 1);
    STAGE_B(0, 0, k0 + 128);
    BAR(); WAIT_LGKM0(); SCHEDB();
    MFMA_QUAD(1, 1, rb1);
    SCHEDB(); BAR(); SCHEDB();
    // ph4
    STAGE_B(0, 1, k0 + 128);
    BAR(); SCHEDB();
    MFMA_QUAD(1, 0, rb0);
    WAIT_VM4(); SCHEDB(); BAR(); SCHEDB();
    // ph5
    LOAD_A(1, 0); LOAD_B(1, 0, rb0);
    STAGE_A(0, 0, k0 + 128);
    BAR(); WAIT_LGKM0(); SCHEDB();
    MFMA_QUAD(0, 0, rb0);
    SCHEDB(); BAR(); SCHEDB();
    // ph6
    LOAD_B(1, 1, rb1);
    STAGE_A(0, 1, k0 + 128);
    BAR(); WAIT_LGKM0(); SCHEDB();
    MFMA_QUAD(0, 1, rb1);
    SCHEDB(); BAR(); SCHEDB();
    // ph7
    LOAD_A(1, 1);
    STAGE_B(1, 0, k0 + 192);
    BAR(); WAIT_LGKM0(); SCHEDB();
    MFMA_QUAD(1, 1, rb1);
    SCHEDB(); BAR(); SCHEDB();
    // ph8
    STAGE_B(1, 1, k0 + 192);
    BAR(); SCHEDB();
    MFMA_QUAD(1, 0, rb0);
    WAIT_VM4(); SCHEDB(); BAR(); SCHEDB();
  }

  // ---- epilogue iteration (KT 94, 95): only the pending s1.A stages ----
  {
    size_t k0 = (size_t)47 * 128;
    // ph1
    LOAD_A(0, 0); LOAD_B(0, 0, rb0);
    STAGE_A(1, 0, k0 + 64);
    BAR(); WAIT_LGKM0(); SCHEDB();
    MFMA_QUAD(0, 0, rb0);
    SCHEDB(); BAR(); SCHEDB();
    // ph2
    LOAD_B(0, 1, rb1);
    STAGE_A(1, 1, k0 + 64);
    BAR(); WAIT_LGKM0(); SCHEDB();
    MFMA_QUAD(0, 1, rb1);
    SCHEDB(); BAR(); SCHEDB();
    // ph3
    LOAD_A(0, 1);
    BAR(); WAIT_LGKM0(); SCHEDB();
    MFMA_QUAD(1, 1, rb1);
    SCHEDB(); BAR(); SCHEDB();
    // ph4
    BAR(); SCHEDB();
    MFMA_QUAD(1, 0, rb0);
    WAIT_VM0(); SCHEDB(); BAR(); SCHEDB();
    // ph5
    LOAD_A(1, 0); LOAD_B(1, 0, rb0);
    BAR(); WAIT_LGKM0(); SCHEDB();
    MFMA_QUAD(0, 0, rb0);
    SCHEDB(); BAR(); SCHEDB();
    // ph6
    LOAD_B(1, 1, rb1);
    BAR(); WAIT_LGKM0(); SCHEDB();
    MFMA_QUAD(0, 1, rb1);
    SCHEDB(); BAR(); SCHEDB();
    // ph7
    LOAD_A(1, 1);
    BAR(); WAIT_LGKM0(); SCHEDB();
    MFMA_QUAD(1, 1, rb1);
    SCHEDB(); BAR(); SCHEDB();
    // ph8
    MFMA_QUAD(1, 0, rb0);
  }

  if (coop) {
    // ---- fused epilogue: P1 bf16 -> grid sync -> out = acc + bias + P1 ----
    if (kc) {
      #pragma unroll
      for (int I = 0; I < 8; ++I) {
        int row0 = mt * 256 + wr * 128 + I * 16 + kq * 4;
        #pragma unroll
        for (int J = 0; J < 4; ++J) {
          int col = nt * 256 + wcol * 64 + J * 16 + lrow;
          #pragma unroll
          for (int r = 0; r < 4; ++r)
            P1[(size_t)(row0 + r) * NDIM + col] = f2bf(acc[I][J][r]);
        }
      }
    }
    __threadfence();
    cooperative_groups::this_grid().sync();
    if (!kc) {
      float bv[4];
      #pragma unroll
      for (int J = 0; J < 4; ++J)
        bv[J] = bias[nt * 256 + wcol * 64 + J * 16 + lrow];
      #pragma unroll
      for (int I = 0; I < 8; ++I) {
        int row0 = mt * 256 + wr * 128 + I * 16 + kq * 4;
        #pragma unroll
        for (int J = 0; J < 4; ++J) {
          int col = nt * 256 + wcol * 64 + J * 16 + lrow;
          #pragma unroll
          for (int r = 0; r < 4; ++r) {
            size_t idx = (size_t)(row0 + r) * NDIM + col;
            out[idx] = acc[I][J][r] + bv[J] + bf2f(P1[idx]);
          }
        }
      }
    }
  } else {
    // ---- fallback (round-9): bf16 partials, separate combine ----
    unsigned short* dst = kc ? P1 : P0;
    float bv[4];
    #pragma unroll
    for (int J = 0; J < 4; ++J)
      bv[J] = kc ? 0.f : bias[nt * 256 + wcol * 64 + J * 16 + lrow];
    #pragma unroll
    for (int I = 0; I < 8; ++I) {
      int row0 = mt * 256 + wr * 128 + I * 16 + kq * 4;
      #pragma unroll
      for (int J = 0; J < 4; ++J) {
        int col = nt * 256 + wcol * 64 + J * 16 + lrow;
        #pragma unroll
        for (int r = 0; r < 4; ++r)
          dst[(size_t)(row0 + r) * NDIM + col] = f2bf(acc[I][J][r] + bv[J]);
      }
    }
  }
}

// ---------- combine (fallback only): out = f32(P0) + f32(P1) ----------
__global__ __launch_bounds__(256) void combine(float* __restrict__ out,
                                               const unsigned short* __restrict__ p0,
                                               const unsigned short* __restrict__ p1) {
  size_t n = (size_t)MDIM * NDIM / 8;
  size_t stride = (size_t)gridDim.x * 256;
  for (size_t i = (size_t)blockIdx.x * 256 + threadIdx.x; i < n; i += stride) {
    u16x8 a = *(const u16x8*)(p0 + i * 8);
    u16x8 c = *(const u16x8*)(p1 + i * 8);
    f32x4 lo, hi;
    #pragma unroll
    for (int j = 0; j < 4; ++j) {
      lo[j] = bf2f(a[j]) + bf2f(c[j]);
      hi[j] = bf2f(a[j + 4]) + bf2f(c[j + 4]);
    }
    *(f32x4*)(out + i * 8) = lo;
    *(f32x4*)(out + i * 8 + 4) = hi;
  }
}

extern "C" void kernel_launch(void* const* d_in, const int* in_sizes, int n_in,
                              void* d_out, int out_size, void* d_ws, size_t ws_size,
                              hipStream_t stream) {
  const float* x = (const float*)d_in[0];    // [B,L,D]
  const float* W = (const float*)d_in[1];    // [O=2048, CAT=18432]
  const float* b = (const float*)d_in[2];    // [O]
  float* out = (float*)d_out;                // [B,L,O] f32

  uint8_t* ws = (uint8_t*)d_ws;
  size_t offB0 = 0;
  size_t szB0 = (size_t)NDIM * KCHUNK * 2;          // 25,165,824
  size_t offB1 = offB0 + szB0;
  size_t szB1 = (size_t)2 * NDIM * KCHUNK * 2;      // 50,331,648
  size_t offMx = offB1 + szB1;
  size_t szMx = (size_t)MDIM * KGEMM * 2;           // 100,663,296
  size_t offGlo = offMx + szMx;
  size_t szGlo = (size_t)BDIM * DDIM * 4;           // 16 KB
  size_t offPart = offGlo + szGlo;
  size_t szPart = (size_t)BDIM * 16 * DDIM * 4;     // 256 KB
  size_t offP0 = offPart + szPart;
  size_t szP0 = (size_t)MDIM * NDIM * 2;            // 16,777,216
  size_t offP1 = offP0 + szP0;
  size_t szP1 = (size_t)MDIM * NDIM * 2;            // 16,777,216
  if (ws_size < offP1 + szP1) return;               // ~210 MB < proven budget

  unsigned short* B0 = (unsigned short*)(ws + offB0);
  unsigned short* B1 = (unsigned short*)(ws + offB1);
  unsigned short* Mx = (unsigned short*)(ws + offMx);
  float* glo = (float*)(ws + offGlo);
  float* part = (float*)(ws + offPart);
  unsigned short* P0 = (unsigned short*)(ws + offP0);
  unsigned short* P1 = (unsigned short*)(ws + offP1);

  hipFuncSetAttribute((const void*)gemm256, hipFuncAttributeMaxDynamicSharedMemorySize,
                      131072);

  hipLaunchKernelGGL(glo_partial, dim3(256), dim3(256), 0, stream, x, part);
  hipLaunchKernelGGL(glo_final, dim3(16), dim3(256), 0, stream, part, glo);
  hipLaunchKernelGGL(conv_wB, dim3(5, 2048), dim3(256), 0, stream, W, B0, B1);
  hipLaunchKernelGGL(fold_w, dim3(2048), dim3(256), 0, stream, W, glo, B1);
  hipLaunchKernelGGL(build_mixed, dim3(4096), dim3(256), 0, stream, x, glo, Mx);

  // cooperative fused-epilogue GEMM; fall back to round-9 path on failure
  const unsigned short* Mxc = Mx;
  const unsigned short* B0c = B0;
  const unsigned short* B1c = B1;
  const float* bc = b;
  int coop = 1;
  void* args[] = {(void*)&Mxc, (void*)&B0c, (void*)&B1c, (void*)&bc,
                  (void*)&P0, (void*)&P1, (void*)&out, (void*)&coop};
  hipError_t ce = hipLaunchCooperativeKernel((void*)gemm256, dim3(256), dim3(512),
                                             args, 131072, stream);
  if (ce != hipSuccess) {
    hipLaunchKernelGGL(gemm256, dim3(256), dim3(512), 131072, stream,
                       Mx, B0, B1, b, P0, P1, out, 0);
    hipLaunchKernelGGL(combine, dim3(2048), dim3(256), 0, stream, out, P0, P1);
  }
}

// Round 11
// 267.075 us; speedup vs baseline: 1.4434x; 1.4434x over previous
//
#include <hip/hip_runtime.h>
#include <stdint.h>

#define DDIM 2048
#define LDIM 2048
#define BDIM 2
#define CATK 18432    // 9*D  (original W col count)
#define MDIM 4096     // B*L
#define NDIM 2048
#define KGEMM 12288   // 6*D : [silu(x) | inner1 | inner2 | inner4 | inner8 | x]
#define KCHUNK 6144   // split-K=2; also the row stride of B0/B1

typedef short bf16x8 __attribute__((ext_vector_type(8)));
typedef float f32x4 __attribute__((ext_vector_type(4)));
typedef unsigned short u16x8 __attribute__((ext_vector_type(8)));

__device__ __forceinline__ unsigned short f2bf(float f) {
  uint32_t u = __float_as_uint(f);
  return (unsigned short)((u + 0x7fffu + ((u >> 16) & 1u)) >> 16);
}
__device__ __forceinline__ float bf2f(unsigned short h) {
  return __uint_as_float((uint32_t)h << 16);
}
__device__ __forceinline__ float silu_f(float v) { return v / (1.0f + __expf(-v)); }

__device__ __forceinline__ void async16(const void* g, void* l) {
  __builtin_amdgcn_global_load_lds(
      (const __attribute__((address_space(1))) uint32_t*)(uintptr_t)g,
      (__attribute__((address_space(3))) uint32_t*)(uintptr_t)l, 16, 0, 0);
}

// ---------- glo = mean_L(x) : two-stage ----------
__global__ __launch_bounds__(256) void glo_partial(const float* __restrict__ x,
                                                   float* __restrict__ part) {
  int g = blockIdx.x;                 // 256 blocks = b(2) * sl(16) * dc(8)
  int dc = g & 7, sl = (g >> 3) & 15, b = g >> 7;
  int d = dc * 256 + threadIdx.x;
  const float* p = x + ((size_t)b * LDIM + (size_t)sl * 128) * DDIM + d;
  float s = 0.f;
  #pragma unroll 8
  for (int i = 0; i < 128; ++i) s += p[(size_t)i * DDIM];
  part[(size_t)(b * 16 + sl) * DDIM + d] = s;
}

__global__ __launch_bounds__(256) void glo_final(const float* __restrict__ part,
                                                 float* __restrict__ glo) {
  int idx = blockIdx.x * 256 + threadIdx.x;   // 0..4095 = b*2048+d
  int b = idx >> 11, d = idx & 2047;
  float s = 0.f;
  #pragma unroll
  for (int i = 0; i < 16; ++i) s += part[(size_t)(b * 16 + i) * DDIM + d];
  glo[idx] = s * (1.0f / (float)LDIM);
}

// ---------- W common blocks f32 -> bf16 into per-chunk B arrays ----------
// B0[o][6144]     <- W blocks {0(silu),1(i1),3(i2)}   written ONCE
// B1[b][o][6144]  <- cols 0..4095: W blocks {5(i4),7(i8)} duplicated per b
//                    cols 4096..6143: V_b (written by fold_w)
__global__ __launch_bounds__(256) void conv_wB(const float* __restrict__ W,
                                               unsigned short* __restrict__ B0,
                                               unsigned short* __restrict__ B1) {
  int k = blockIdx.x;                 // 0..4
  int o = blockIdx.y;                 // row 0..2047
  int srcb = (k == 0) ? 0 : (k == 1) ? 1 : (k == 2) ? 3 : (k == 3) ? 5 : 7;
  const float* src = W + (size_t)o * CATK + srcb * 2048 + threadIdx.x * 8;
  f32x4 a = *(const f32x4*)src;
  f32x4 c = *(const f32x4*)(src + 4);
  u16x8 v;
  v[0] = f2bf(a[0]); v[1] = f2bf(a[1]); v[2] = f2bf(a[2]); v[3] = f2bf(a[3]);
  v[4] = f2bf(c[0]); v[5] = f2bf(c[1]); v[6] = f2bf(c[2]); v[7] = f2bf(c[3]);
  if (k < 3) {
    *(u16x8*)(B0 + (size_t)o * KCHUNK + k * 2048 + threadIdx.x * 8) = v;
  } else {
    size_t d = (size_t)o * KCHUNK + (size_t)(k - 3) * 2048 + threadIdx.x * 8;
    *(u16x8*)(B1 + d) = v;
    *(u16x8*)(B1 + (size_t)2048 * KCHUNK + d) = v;
  }
}

// ---------- fold wedge blocks into per-batch effective weights ----------
// V_b[o,d] = sum_s ( Ws[o,d]*g_b[(d-s)&2047] - Ws[o,(d+s)&2047]*g_b[(d+s)&2047] )
// s = 1,2,4,8 ; Ws = W block (2+2j). Both batches per block: W read ONCE.
// Written to B1[b][o][4096 + d].
__global__ __launch_bounds__(256) void fold_w(const float* __restrict__ W,
                                              const float* __restrict__ glo,
                                              unsigned short* __restrict__ B1) {
  __shared__ float ws[4][2048];
  __shared__ float g2[2][2048];
  int o = blockIdx.x;
  for (int i = threadIdx.x; i < 512; i += 256) {
    *(f32x4*)&g2[0][i * 4] = *(const f32x4*)&glo[i * 4];
    *(f32x4*)&g2[1][i * 4] = *(const f32x4*)&glo[2048 + i * 4];
    #pragma unroll
    for (int j = 0; j < 4; ++j)
      *(f32x4*)&ws[j][i * 4] =
          *(const f32x4*)(W + (size_t)o * CATK + (2 + 2 * j) * 2048 + i * 4);
  }
  __syncthreads();
  int d0 = threadIdx.x * 8;
  #pragma unroll
  for (int b = 0; b < 2; ++b) {
    u16x8 outv;
    #pragma unroll
    for (int e = 0; e < 8; ++e) {
      int d = d0 + e;
      float v = 0.f;
      #pragma unroll
      for (int j = 0; j < 4; ++j) {
        int s = 1 << j;
        int dm = (d - s) & 2047, dp = (d + s) & 2047;
        v += ws[j][d] * g2[b][dm] - ws[j][dp] * g2[b][dp];
      }
      outv[e] = f2bf(v);
    }
    *(u16x8*)(B1 + (size_t)b * 2048 * KCHUNK + (size_t)o * KCHUNK + 4096 + d0) = outv;
  }
}

// ---------- build A features (bf16): [silu(x) | inner(1,2,4,8) | x] ----------
__global__ __launch_bounds__(256) void build_mixed(const float* __restrict__ x,
                                                   const float* __restrict__ glo,
                                                   unsigned short* __restrict__ mixed) {
  __shared__ float xs[DDIM];
  __shared__ float gs[DDIM];
  int row = blockIdx.x;              // 0..4095
  int b = row >> 11;
  const float* xr = x + (size_t)row * DDIM;
  const float* gr = glo + (size_t)b * DDIM;
  for (int i = threadIdx.x; i < DDIM / 4; i += 256) {
    *(f32x4*)&xs[i * 4] = *(const f32x4*)&xr[i * 4];
    *(f32x4*)&gs[i * 4] = *(const f32x4*)&gr[i * 4];
  }
  __syncthreads();
  unsigned short* mr = mixed + (size_t)row * KGEMM;
  int d0 = threadIdx.x * 8;
  u16x8 o0, oi[4], xb;
  #pragma unroll
  for (int j = 0; j < 8; ++j) {
    int d = d0 + j;
    float xv = xs[d];
    o0[j] = f2bf(silu_f(xv));
    xb[j] = f2bf(xv);
    #pragma unroll
    for (int si = 0; si < 4; ++si) {
      int s = 1 << si;
      int dm = (d - s) & (DDIM - 1);
      oi[si][j] = f2bf(silu_f(xv * gs[dm]));
    }
  }
  *(u16x8*)(mr + d0) = o0;
  #pragma unroll
  for (int si = 0; si < 4; ++si)
    *(u16x8*)(mr + (size_t)(1 + si) * DDIM + d0) = oi[si];
  *(u16x8*)(mr + (size_t)10240 + d0) = xb;
}

// ---------- 256x256 8-phase GEMM (T2+T3+T4+T5), split-K=2 ----------
// FINAL (round-9 state, probe-converged): 1 stage per phase, vmcnt(4)
// @ph4/ph8, XOR-swizzled LDS (0 conflicts), XCD-swizzled grid, bf16 split-K
// partials (P0 = bias+half0, P1 = half1) + separate combine.
// Probed and rejected: burst-lgkm (r5, +6us), deep-vmcnt clustered stages
// (r8, +20us), cooperative fused epilogue (r10, +90us grid-sync skew).
#define BAR() __builtin_amdgcn_s_barrier()
#define SCHEDB() __builtin_amdgcn_sched_barrier(0)
#define WAIT_VM4() asm volatile("s_waitcnt vmcnt(4)" ::: "memory")
#define WAIT_VM0() asm volatile("s_waitcnt vmcnt(0)" ::: "memory")
#define WAIT_LGKM0() asm volatile("s_waitcnt lgkmcnt(0)" ::: "memory")

#define STAGE_A(S, H, KREL)                                            \
  do {                                                                 \
    const unsigned short* g_ = gA + (size_t)((H)*128) * KGEMM + (KREL);\
    unsigned short* l_ = stA + ((S)*2 + (H)) * 8192;                   \
    async16(g_, l_);                                                   \
    async16(g_ + (size_t)8 * KGEMM, l_ + 512);                         \
  } while (0)

#define STAGE_B(S, H, KREL)                                             \
  do {                                                                  \
    const unsigned short* g_ = gB + (size_t)((H)*128) * KCHUNK + (KREL);\
    unsigned short* l_ = stB + ((S)*2 + (H)) * 8192;                    \
    async16(g_, l_);                                                    \
    async16(g_ + (size_t)8 * KCHUNK, l_ + 512);                         \
  } while (0)

#define LOAD_A(S, MH)                                                        \
  do {                                                                       \
    _Pragma("unroll") for (int mi = 0; mi < 4; ++mi) {                       \
      ra[mi][0] = *(const bf16x8*)(pA + (S)*16384 + ((MH)*64 + mi*16)*64 + sl0); \
      ra[mi][1] = *(const bf16x8*)(pA + (S)*16384 + ((MH)*64 + mi*16)*64 + sl1); \
    }                                                                        \
  } while (0)

#define LOAD_B(S, NH, RB)                                                    \
  do {                                                                       \
    _Pragma("unroll") for (int nj = 0; nj < 2; ++nj) {                       \
      RB[nj][0] = *(const bf16x8*)(pB + (S)*16384 + ((NH)*32 + nj*16)*64 + sl0); \
      RB[nj][1] = *(const bf16x8*)(pB + (S)*16384 + ((NH)*32 + nj*16)*64 + sl1); \
    }                                                                        \
  } while (0)

#define MFMA_QUAD(MH, NH, RB)                                                \
  do {                                                                       \
    __builtin_amdgcn_s_setprio(1);                                           \
    _Pragma("unroll") for (int kk = 0; kk < 2; ++kk)                         \
      _Pragma("unroll") for (int mi = 0; mi < 4; ++mi)                       \
        _Pragma("unroll") for (int nj = 0; nj < 2; ++nj)                     \
          acc[(MH)*4 + mi][(NH)*2 + nj] = __builtin_amdgcn_mfma_f32_16x16x32_bf16( \
              ra[mi][kk], RB[nj][kk], acc[(MH)*4 + mi][(NH)*2 + nj], 0, 0, 0);     \
    __builtin_amdgcn_s_setprio(0);                                           \
  } while (0)

__global__ __launch_bounds__(512, 2) void gemm256(const unsigned short* __restrict__ A,
                                                  const unsigned short* __restrict__ B0,
                                                  const unsigned short* __restrict__ B1,
                                                  const float* __restrict__ bias,
                                                  unsigned short* __restrict__ P0,
                                                  unsigned short* __restrict__ P1) {
  extern __shared__ unsigned short lds[];
  unsigned short* ldsA = lds;            // [s][h][128][64]
  unsigned short* ldsB = lds + 32768;

  int bid = blockIdx.x;                  // 256 blocks
  int swz = (bid & 7) * 32 + (bid >> 3); // XCD-contiguous, bijective (256%8==0)
  int kc = swz >> 7;                     // split-K chunk
  int rem = swz & 127;
  int mt = rem >> 3, nt = rem & 7;       // 16 x 8 tiles of 256^2
  size_t kbase = (size_t)kc * KCHUNK;

  int tid = threadIdx.x;
  int wave = tid >> 6, lane = tid & 63;
  int wr = wave >> 2, wcol = wave & 3;   // 2M x 4N waves
  int lrow = lane & 15, kq = lane >> 4, r3 = lrow & 7;
  int rIn8 = lane >> 3;
  int scOff = ((lane & 7) ^ rIn8) * 8;   // pre-swizzled source chunk
  int wv16 = wave * 16;

  const unsigned short* gA = A + (size_t)(mt * 256 + wv16 + rIn8) * KGEMM + kbase + scOff;
  const unsigned short* gBb = kc ? (B1 + (size_t)((mt >= 8) ? 2048 : 0) * KCHUNK) : B0;
  const unsigned short* gB = gBb + (size_t)(nt * 256 + wv16 + rIn8) * KCHUNK + scOff;
  unsigned short* stA = ldsA + wv16 * 64;  // wave-uniform LDS stage base
  unsigned short* stB = ldsB + wv16 * 64;

  const unsigned short* pA = ldsA + wr * 8192 + lrow * 64;
  const unsigned short* pB = ldsB + (wcol >> 1) * 8192 + ((wcol & 1) * 64 + lrow) * 64;
  int sl0 = (kq ^ r3) * 8, sl1 = ((kq + 4) ^ r3) * 8;

  f32x4 acc[8][4];
  #pragma unroll
  for (int i = 0; i < 8; ++i)
    #pragma unroll
    for (int j = 0; j < 4; ++j) acc[i][j] = (f32x4)0.f;
  bf16x8 ra[4][2], rb0[2][2], rb1[2][2];

  // ---- prologue: KT0 (s0) all 4 halves + KT1 (s1) B halves ----
  STAGE_B(0, 0, 0); STAGE_B(0, 1, 0);
  STAGE_A(0, 0, 0); STAGE_A(0, 1, 0);
  STAGE_B(1, 0, 64); STAGE_B(1, 1, 64);
  WAIT_VM4(); SCHEDB();
  BAR(); SCHEDB();

  // ---- main loop: 47 full iterations (KT 0..93), staging 2 K-tiles ahead ----
  for (int t = 0; t < 47; ++t) {
    size_t k0 = (size_t)t * 128;
    // ph1
    LOAD_A(0, 0); LOAD_B(0, 0, rb0);
    STAGE_A(1, 0, k0 + 64);
    BAR(); WAIT_LGKM0(); SCHEDB();
    MFMA_QUAD(0, 0, rb0);
    SCHEDB(); BAR(); SCHEDB();
    // ph2
    LOAD_B(0, 1, rb1);
    STAGE_A(1, 1, k0 + 64);
    BAR(); WAIT_LGKM0(); SCHEDB();
    MFMA_QUAD(0, 1, rb1);
    SCHEDB(); BAR(); SCHEDB();
    // ph3
    LOAD_A(0, 1);
    STAGE_B(0, 0, k0 + 128);
    BAR(); WAIT_LGKM0(); SCHEDB();
    MFMA_QUAD(1, 1, rb1);
    SCHEDB(); BAR(); SCHEDB();
    // ph4
    STAGE_B(0, 1, k0 + 128);
    BAR(); SCHEDB();
    MFMA_QUAD(1, 0, rb0);
    WAIT_VM4(); SCHEDB(); BAR(); SCHEDB();
    // ph5
    LOAD_A(1, 0); LOAD_B(1, 0, rb0);
    STAGE_A(0, 0, k0 + 128);
    BAR(); WAIT_LGKM0(); SCHEDB();
    MFMA_QUAD(0, 0, rb0);
    SCHEDB(); BAR(); SCHEDB();
    // ph6
    LOAD_B(1, 1, rb1);
    STAGE_A(0, 1, k0 + 128);
    BAR(); WAIT_LGKM0(); SCHEDB();
    MFMA_QUAD(0, 1, rb1);
    SCHEDB(); BAR(); SCHEDB();
    // ph7
    LOAD_A(1, 1);
    STAGE_B(1, 0, k0 + 192);
    BAR(); WAIT_LGKM0(); SCHEDB();
    MFMA_QUAD(1, 1, rb1);
    SCHEDB(); BAR(); SCHEDB();
    // ph8
    STAGE_B(1, 1, k0 + 192);
    BAR(); SCHEDB();
    MFMA_QUAD(1, 0, rb0);
    WAIT_VM4(); SCHEDB(); BAR(); SCHEDB();
  }

  // ---- epilogue iteration (KT 94, 95): only the pending s1.A stages ----
  {
    size_t k0 = (size_t)47 * 128;
    // ph1
    LOAD_A(0, 0); LOAD_B(0, 0, rb0);
    STAGE_A(1, 0, k0 + 64);
    BAR(); WAIT_LGKM0(); SCHEDB();
    MFMA_QUAD(0, 0, rb0);
    SCHEDB(); BAR(); SCHEDB();
    // ph2
    LOAD_B(0, 1, rb1);
    STAGE_A(1, 1, k0 + 64);
    BAR(); WAIT_LGKM0(); SCHEDB();
    MFMA_QUAD(0, 1, rb1);
    SCHEDB(); BAR(); SCHEDB();
    // ph3
    LOAD_A(0, 1);
    BAR(); WAIT_LGKM0(); SCHEDB();
    MFMA_QUAD(1, 1, rb1);
    SCHEDB(); BAR(); SCHEDB();
    // ph4
    BAR(); SCHEDB();
    MFMA_QUAD(1, 0, rb0);
    WAIT_VM0(); SCHEDB(); BAR(); SCHEDB();
    // ph5
    LOAD_A(1, 0); LOAD_B(1, 0, rb0);
    BAR(); WAIT_LGKM0(); SCHEDB();
    MFMA_QUAD(0, 0, rb0);
    SCHEDB(); BAR(); SCHEDB();
    // ph6
    LOAD_B(1, 1, rb1);
    BAR(); WAIT_LGKM0(); SCHEDB();
    MFMA_QUAD(0, 1, rb1);
    SCHEDB(); BAR(); SCHEDB();
    // ph7
    LOAD_A(1, 1);
    BAR(); WAIT_LGKM0(); SCHEDB();
    MFMA_QUAD(1, 1, rb1);
    SCHEDB(); BAR(); SCHEDB();
    // ph8
    MFMA_QUAD(1, 0, rb0);
  }

  // ---- C write: bf16 partial (kc=0 folds bias) ----
  unsigned short* dst = kc ? P1 : P0;
  float bv[4];
  #pragma unroll
  for (int J = 0; J < 4; ++J)
    bv[J] = kc ? 0.f : bias[nt * 256 + wcol * 64 + J * 16 + lrow];
  #pragma unroll
  for (int I = 0; I < 8; ++I) {
    int row0 = mt * 256 + wr * 128 + I * 16 + kq * 4;
    #pragma unroll
    for (int J = 0; J < 4; ++J) {
      int col = nt * 256 + wcol * 64 + J * 16 + lrow;
      #pragma unroll
      for (int r = 0; r < 4; ++r)
        dst[(size_t)(row0 + r) * NDIM + col] = f2bf(acc[I][J][r] + bv[J]);
    }
  }
}

// ---------- combine: out = f32(P0) + f32(P1) ----------
__global__ __launch_bounds__(256) void combine(float* __restrict__ out,
                                               const unsigned short* __restrict__ p0,
                                               const unsigned short* __restrict__ p1) {
  size_t n = (size_t)MDIM * NDIM / 8;
  size_t stride = (size_t)gridDim.x * 256;
  for (size_t i = (size_t)blockIdx.x * 256 + threadIdx.x; i < n; i += stride) {
    u16x8 a = *(const u16x8*)(p0 + i * 8);
    u16x8 c = *(const u16x8*)(p1 + i * 8);
    f32x4 lo, hi;
    #pragma unroll
    for (int j = 0; j < 4; ++j) {
      lo[j] = bf2f(a[j]) + bf2f(c[j]);
      hi[j] = bf2f(a[j + 4]) + bf2f(c[j + 4]);
    }
    *(f32x4*)(out + i * 8) = lo;
    *(f32x4*)(out + i * 8 + 4) = hi;
  }
}

extern "C" void kernel_launch(void* const* d_in, const int* in_sizes, int n_in,
                              void* d_out, int out_size, void* d_ws, size_t ws_size,
                              hipStream_t stream) {
  const float* x = (const float*)d_in[0];    // [B,L,D]
  const float* W = (const float*)d_in[1];    // [O=2048, CAT=18432]
  const float* b = (const float*)d_in[2];    // [O]
  float* out = (float*)d_out;                // [B,L,O] f32

  uint8_t* ws = (uint8_t*)d_ws;
  size_t offB0 = 0;
  size_t szB0 = (size_t)NDIM * KCHUNK * 2;          // 25,165,824
  size_t offB1 = offB0 + szB0;
  size_t szB1 = (size_t)2 * NDIM * KCHUNK * 2;      // 50,331,648
  size_t offMx = offB1 + szB1;
  size_t szMx = (size_t)MDIM * KGEMM * 2;           // 100,663,296
  size_t offGlo = offMx + szMx;
  size_t szGlo = (size_t)BDIM * DDIM * 4;           // 16 KB
  size_t offPart = offGlo + szGlo;
  size_t szPart = (size_t)BDIM * 16 * DDIM * 4;     // 256 KB
  size_t offP0 = offPart + szPart;
  size_t szP0 = (size_t)MDIM * NDIM * 2;            // 16,777,216
  size_t offP1 = offP0 + szP0;
  size_t szP1 = (size_t)MDIM * NDIM * 2;            // 16,777,216
  if (ws_size < offP1 + szP1) return;               // ~210 MB < proven budget

  unsigned short* B0 = (unsigned short*)(ws + offB0);
  unsigned short* B1 = (unsigned short*)(ws + offB1);
  unsigned short* Mx = (unsigned short*)(ws + offMx);
  float* glo = (float*)(ws + offGlo);
  float* part = (float*)(ws + offPart);
  unsigned short* P0 = (unsigned short*)(ws + offP0);
  unsigned short* P1 = (unsigned short*)(ws + offP1);

  hipFuncSetAttribute((const void*)gemm256, hipFuncAttributeMaxDynamicSharedMemorySize,
                      131072);

  hipLaunchKernelGGL(glo_partial, dim3(256), dim3(256), 0, stream, x, part);
  hipLaunchKernelGGL(glo_final, dim3(16), dim3(256), 0, stream, part, glo);
  hipLaunchKernelGGL(conv_wB, dim3(5, 2048), dim3(256), 0, stream, W, B0, B1);
  hipLaunchKernelGGL(fold_w, dim3(2048), dim3(256), 0, stream, W, glo, B1);
  hipLaunchKernelGGL(build_mixed, dim3(4096), dim3(256), 0, stream, x, glo, Mx);

  hipLaunchKernelGGL(gemm256, dim3(256), dim3(512), 131072, stream, Mx, B0, B1, b, P0, P1);
  hipLaunchKernelGGL(combine, dim3(2048), dim3(256), 0, stream, out, P0, P1);
}